// Round 11
// baseline (104.854 us; speedup 1.0000x reference)
//
#include <hip/hip_runtime.h>

#define NPOS 4096      // H*W
#define NCH  256       // channels
#define HD   32        // head dim
#define KB   128       // keys per attention step
#define NSPLIT 4
#define SPLIT_KEYS (NPOS / NSPLIT)
#define NSTEP (SPLIT_KEYS / KB)

typedef float f32x4  __attribute__((ext_vector_type(4)));
typedef float f32x16 __attribute__((ext_vector_type(16)));
typedef short s16x8  __attribute__((ext_vector_type(8)));
typedef uint  u32x2  __attribute__((ext_vector_type(2)));
typedef uint  u32x4  __attribute__((ext_vector_type(4)));
typedef int   i32x2  __attribute__((ext_vector_type(2)));

static __device__ __forceinline__ s16x8 load8(const ushort* p) {
    return *(const s16x8*)p;
}
static __device__ __forceinline__ ushort bfbits(float x) {
    __bf16 b = (__bf16)x;
    return __builtin_bit_cast(unsigned short, b);
}
static __device__ __forceinline__ float bfval(ushort u) {
    uint x = (uint)u << 16;
    return __builtin_bit_cast(float, x);
}
static __device__ __forceinline__ uint pk2(float a, float b) {
    return (uint)bfbits(a) | ((uint)bfbits(b) << 16);
}
// permlane32_swap: a -> (a_lo, b_lo-from-partner), b -> (a_hi, b_hi)
static __device__ __forceinline__ void plswap(uint& a, uint& b) {
    i32x2 r = __builtin_amdgcn_permlane32_swap((int)a, (int)b, false, false);
    a = (uint)r[0];
    b = (uint)r[1];
}

// ---------------- fused input conversion ----------------
// z=0: x1 -> xt1 hi/lo [4096][256]; z=1: x2 -> xt2; z=2: W matrices -> wsp.
__global__ __launch_bounds__(256) void convert_kernel(
    const float* __restrict__ x1, const float* __restrict__ x2,
    const float* __restrict__ Wq, const float* __restrict__ Wk,
    const float* __restrict__ Wv, const float* __restrict__ Wp,
    ushort* __restrict__ xt1h, ushort* __restrict__ xt1l,
    ushort* __restrict__ xt2h, ushort* __restrict__ xt2l,
    ushort* __restrict__ wsp, float qscale)
{
    if (blockIdx.z == 2) {
        const int m = blockIdx.y;
        const float* src = m == 0 ? Wq : m == 1 ? Wk : m == 2 ? Wv : Wp;
        const float sc = m == 0 ? qscale : 1.f;
        const int idx = (blockIdx.x * 256 + threadIdx.x) * 4;
        f32x4 w = *(const f32x4*)(src + idx);
        w *= sc;
        ushort h[4], l[4];
#pragma unroll
        for (int i = 0; i < 4; ++i) {
            h[i] = bfbits(w[i]);
            l[i] = bfbits(w[i] - bfval(h[i]));
        }
        ushort* H = wsp + m * 2 * 65536;
        *(u32x2*)(H + idx)         = (u32x2){(uint)h[0] | ((uint)h[1] << 16),
                                             (uint)h[2] | ((uint)h[3] << 16)};
        *(u32x2*)(H + 65536 + idx) = (u32x2){(uint)l[0] | ((uint)l[1] << 16),
                                             (uint)l[2] | ((uint)l[3] << 16)};
        return;
    }
    __shared__ float tile[64][65];
    const float* X = blockIdx.z ? x2 : x1;
    ushort* Hd = blockIdx.z ? xt2h : xt1h;
    ushort* Ld = blockIdx.z ? xt2l : xt1l;
    const int n0 = blockIdx.x * 64, c0 = blockIdx.y * 64;
    const int tj = threadIdx.x & 63, ti = threadIdx.x >> 6;
#pragma unroll
    for (int r = 0; r < 16; ++r) {
        int i = r * 4 + ti;
        tile[i][tj] = X[(c0 + i) * NPOS + n0 + tj];
    }
    __syncthreads();
#pragma unroll
    for (int r = 0; r < 16; ++r) {
        int i = r * 4 + ti;                       // n offset
        float v = tile[tj][i];                    // X[c0+tj][n0+i]
        ushort h = bfbits(v);
        ushort l = bfbits(v - bfval(h));
        Hd[(n0 + i) * NCH + c0 + tj] = h;
        Ld[(n0 + i) * NCH + c0 + tj] = l;
    }
}

// ---------------- fused QKV projection (bf16x3 MFMA) ----------------
// grid (128, 12): y>>2 = m (0 Q from x1, 1 K from x2, 2 V from x2), y&3 = ob.
__global__ __launch_bounds__(256) void gemm_qkv_kernel(
    const ushort* __restrict__ wsp,
    const ushort* __restrict__ x1h, const ushort* __restrict__ x1l,
    const ushort* __restrict__ x2h, const ushort* __restrict__ x2l,
    ushort* __restrict__ qt, ushort* __restrict__ kt, ushort* __restrict__ vt)
{
    const int m  = blockIdx.y >> 2;
    const int ob = blockIdx.y & 3;
    const ushort* Wh = wsp + m * 131072;
    const ushort* Wl = Wh + 65536;
    const ushort* Bh = (m == 0) ? x1h : x2h;
    const ushort* Bl = (m == 0) ? x1l : x2l;

    const int wid = threadIdx.x >> 6, lane = threadIdx.x & 63;
    const int lq = lane & 15, grp = lane >> 4;
    const int o0 = ob * 64 + wid * 16;
    const int n0 = blockIdx.x * 32;
    const int woff = (o0 + lq) * NCH + grp * 8;
    const int boff = (n0 + lq) * NCH + grp * 8;

    f32x4 acc[2];
    acc[0] = (f32x4){0.f, 0.f, 0.f, 0.f};
    acc[1] = acc[0];
#pragma unroll
    for (int kc = 0; kc < 8; ++kc) {
        const s16x8 ah = load8(Wh + woff + kc * 32);
        const s16x8 al = load8(Wl + woff + kc * 32);
#pragma unroll
        for (int nt = 0; nt < 2; ++nt) {
            const s16x8 bh = load8(Bh + boff + nt * 16 * NCH + kc * 32);
            const s16x8 bl = load8(Bl + boff + nt * 16 * NCH + kc * 32);
            acc[nt] = __builtin_amdgcn_mfma_f32_16x16x32_bf16(ah, bh, acc[nt], 0, 0, 0);
            acc[nt] = __builtin_amdgcn_mfma_f32_16x16x32_bf16(ah, bl, acc[nt], 0, 0, 0);
            acc[nt] = __builtin_amdgcn_mfma_f32_16x16x32_bf16(al, bh, acc[nt], 0, 0, 0);
        }
    }
    if (m < 2) {
        ushort* Y = m ? kt : qt;
        const int head = o0 >> 5, d0 = (o0 & 31) + grp * 4;
#pragma unroll
        for (int nt = 0; nt < 2; ++nt) {
            const int n = n0 + nt * 16 + lq;
            *(u32x2*)(Y + head * (NPOS * HD) + n * HD + d0) =
                (u32x2){pk2(acc[nt][0], acc[nt][1]), pk2(acc[nt][2], acc[nt][3])};
        }
    } else {
#pragma unroll
        for (int nt = 0; nt < 2; ++nt) {
            const int n = n0 + nt * 16 + lq;
#pragma unroll
            for (int r = 0; r < 4; ++r)
                vt[(o0 + grp * 4 + r) * NPOS + n] = bfbits(acc[nt][r]);
        }
    }
}

// ---- MFMA flash attention: 32x32, no max, LDS dbuf (1 barrier/step) ----
// grid 1024: s = bid>>8, h = bid&7, qblk = (bid&255)>>3. KB=128, 8 steps.
// Software pipeline: QK^T(t+1) issued before softmax(t) so exp2 never
// waits on MFMA latency; staging is write(step+1) -> compute -> barrier.
__global__ __launch_bounds__(256) void attn_mfma_kernel(
    const ushort* __restrict__ Qt,   // [8][4096][32] bf16, pre-scaled s*log2e
    const ushort* __restrict__ Kt,   // [8][4096][32] bf16
    const ushort* __restrict__ Vt,   // [8][32][4096] bf16
    ushort* __restrict__ Opb,        // [4][4096][256] bf16 unnormalized
    float* __restrict__ Ml)          // [4][8][4096] f32 (l)
{
    __shared__ __align__(16) ushort lds[18944];  // K0@0 K1@5120 V0@10240 V1@14592
    const int bid  = blockIdx.x;
    const int s    = bid >> 8;
    const int h    = bid & 7;
    const int qblk = (bid & 255) >> 3;   // 0..31
    const int tid  = threadIdx.x;
    const int wid  = tid >> 6;
    const int lane = tid & 63;
    const int l31  = lane & 31;
    const int hi   = lane >> 5;
    const int q0   = qblk * 128 + wid * 32;
    const int k0   = s * SPLIT_KEYS;
    const int hq   = h * (NPOS * HD);

    s16x8 qf[2];
#pragma unroll
    for (int kh = 0; kh < 2; ++kh)
        qf[kh] = load8(Qt + hq + (q0 + l31) * HD + kh * 16 + hi * 8);

    const int kr0 = tid >> 2, kc0 = tid & 3;
    const ushort* kS = Kt + hq + kr0 * HD + kc0 * 8;
    const int kdst0 = kr0 * 40 + ((kc0 ^ ((kr0 >> 3) & 3)) & 3) * 8;
    const int kdst1 = kdst0 + 64 * 40;

    const int vr0 = tid >> 4, vc0 = tid & 15;
    const ushort* vS = Vt + h * (HD * NPOS) + vr0 * NPOS + vc0 * 8;
    const int vdst0 = vr0 * 136 + ((vc0 ^ ((vr0 >> 3) & 3)) & 15) * 8;
    const int vdst1 = (vr0 + 16) * 136 +
                      ((vc0 ^ (((vr0 + 16) >> 3) & 3)) & 15) * 8;

    const int kx = l31 >> 3;

    s16x8 onesf;
#pragma unroll
    for (int i = 0; i < 8; ++i) onesf[i] = (short)0x3F80;

    f32x16 oacc = {};
    f32x16 accl = {};

    // prologue: tile0 -> buf0; prefetch tile1 into regs
    *(s16x8*)(lds + kdst0)         = load8(kS + (size_t)k0 * HD);
    *(s16x8*)(lds + kdst1)         = load8(kS + (size_t)k0 * HD + 64 * HD);
    *(s16x8*)(lds + 10240 + vdst0) = load8(vS + k0);
    *(s16x8*)(lds + 10240 + vdst1) = load8(vS + k0 + 16 * NPOS);
    int m1 = (NSTEP > 1) ? k0 + KB : k0;
    s16x8 kra = load8(kS + (size_t)m1 * HD);
    s16x8 krb = load8(kS + (size_t)m1 * HD + 64 * HD);
    s16x8 vra = load8(vS + m1);
    s16x8 vrb = load8(vS + m1 + 16 * NPOS);
    __syncthreads();

    for (int step = 0; step < NSTEP; ++step) {
        const int cur = step & 1;
        ushort* const Kb = lds + cur * 5120;
        ushort* const Vb = lds + 10240 + cur * 4352;

        // write prefetched tile (step+1) into the other buffer
        {
            ushort* const Kn = lds + (cur ^ 1) * 5120;
            ushort* const Vn = lds + 10240 + (cur ^ 1) * 4352;
            *(s16x8*)(Kn + kdst0) = kra;
            *(s16x8*)(Kn + kdst1) = krb;
            *(s16x8*)(Vn + vdst0) = vra;
            *(s16x8*)(Vn + vdst1) = vrb;
        }
        // issue loads for tile step+2
        const int mn = (step + 2 < NSTEP) ? k0 + (step + 2) * KB : k0;
        kra = load8(kS + (size_t)mn * HD);
        krb = load8(kS + (size_t)mn * HD + 64 * HD);
        vra = load8(vS + mn);
        vrb = load8(vS + mn + 16 * NPOS);

        // --- compute buf[cur], QK^T one tile ahead ---
        f32x16 stc = {};
        {
            const s16x8 kfa = *(const s16x8*)(Kb + l31 * 40 + ((hi ^ kx) & 3) * 8);
            const s16x8 kfb = *(const s16x8*)(Kb + l31 * 40 + (((2 + hi) ^ kx) & 3) * 8);
            __builtin_amdgcn_s_setprio(1);
            stc = __builtin_amdgcn_mfma_f32_32x32x16_bf16(kfa, qf[0], stc, 0, 0, 0);
            stc = __builtin_amdgcn_mfma_f32_32x32x16_bf16(kfb, qf[1], stc, 0, 0, 0);
            __builtin_amdgcn_s_setprio(0);
        }
#pragma unroll
        for (int t = 0; t < 4; ++t) {
            f32x16 stn = {};
            if (t < 3) {
                const int krow = ((t + 1) * 32 + l31) * 40;
                const s16x8 kfa = *(const s16x8*)(Kb + krow + ((hi ^ kx) & 3) * 8);
                const s16x8 kfb = *(const s16x8*)(Kb + krow + (((2 + hi) ^ kx) & 3) * 8);
                __builtin_amdgcn_s_setprio(1);
                stn = __builtin_amdgcn_mfma_f32_32x32x16_bf16(kfa, qf[0], stn, 0, 0, 0);
                stn = __builtin_amdgcn_mfma_f32_32x32x16_bf16(kfb, qf[1], stn, 0, 0, 0);
                __builtin_amdgcn_s_setprio(0);
            }
            const s16x8 vf0 = *(const s16x8*)(Vb + l31 * 136 +
                                              (((t * 4 + hi) ^ kx) & 15) * 8);
            const s16x8 vf1 = *(const s16x8*)(Vb + l31 * 136 +
                                              (((t * 4 + 2 + hi) ^ kx) & 15) * 8);

            uint w[4], w2[4];
#pragma unroll
            for (int g = 0; g < 4; ++g) {
                const float p0 = __builtin_amdgcn_exp2f(stc[4 * g + 0]);
                const float p1 = __builtin_amdgcn_exp2f(stc[4 * g + 1]);
                const float p2 = __builtin_amdgcn_exp2f(stc[4 * g + 2]);
                const float p3 = __builtin_amdgcn_exp2f(stc[4 * g + 3]);
                w[g]  = pk2(p0, p1);
                w2[g] = pk2(p2, p3);
            }
            uint a0 = w[0],  c0 = w[1];  plswap(a0, c0);
            uint a1 = w2[0], c1 = w2[1]; plswap(a1, c1);
            const s16x8 pfA = __builtin_bit_cast(s16x8, (u32x4){a0, a1, c0, c1});
            uint b0 = w[2],  d0 = w[3];  plswap(b0, d0);
            uint b1 = w2[2], d1 = w2[3]; plswap(b1, d1);
            const s16x8 pfB = __builtin_bit_cast(s16x8, (u32x4){b0, b1, d0, d1});

            __builtin_amdgcn_s_setprio(1);
            oacc = __builtin_amdgcn_mfma_f32_32x32x16_bf16(vf0, pfA, oacc, 0, 0, 0);
            oacc = __builtin_amdgcn_mfma_f32_32x32x16_bf16(vf1, pfB, oacc, 0, 0, 0);
            accl = __builtin_amdgcn_mfma_f32_32x32x16_bf16(onesf, pfA, accl, 0, 0, 0);
            accl = __builtin_amdgcn_mfma_f32_32x32x16_bf16(onesf, pfB, accl, 0, 0, 0);
            __builtin_amdgcn_s_setprio(0);

            stc = stn;
        }

        __syncthreads();
    }

    // --- write unnormalized partials (bf16, n-major) + l ---
    const int n = q0 + l31;
    ushort* Ops = Opb + (size_t)s * (NPOS * NCH) + n * NCH + h * HD;
#pragma unroll
    for (int g = 0; g < 4; ++g) {
        *(u32x2*)(Ops + g * 8 + hi * 4) =
            (u32x2){pk2(oacc[4 * g + 0], oacc[4 * g + 1]),
                    pk2(oacc[4 * g + 2], oacc[4 * g + 3])};
    }
    if (lane < 32)
        Ml[(s * 8 + h) * NPOS + n] = accl[0];
}

// ---- output projection, fused split-K combine (bf16x3 MFMA) ----
// B-fragments built in-register: f = (sum of 4 bf16 partials) * inv_l(n,h),
// hi/lo split on the fly. Bitwise identical to combine+gemm_out.
__global__ __launch_bounds__(256) void gemm_out_kernel(
    const ushort* __restrict__ Wh, const ushort* __restrict__ Wl,
    const ushort* __restrict__ Opb, const float* __restrict__ Ml,
    const float* __restrict__ bias, float* __restrict__ Y)
{
    __shared__ float inv_lds[256];   // [head][n_local 0..31]
    const int n0 = blockIdx.x * 32;
    {
        const int hh = threadIdx.x >> 5, nl = threadIdx.x & 31;
        const int n = n0 + nl;
        float l = 0.f;
#pragma unroll
        for (int sp = 0; sp < NSPLIT; ++sp)
            l += Ml[(sp * 8 + hh) * NPOS + n];
        inv_lds[hh * 32 + nl] = 1.f / l;
    }
    __syncthreads();

    const int wid = threadIdx.x >> 6, lane = threadIdx.x & 63;
    const int lq = lane & 15, grp = lane >> 4;
    const int o0 = blockIdx.y * 64 + wid * 16;
    const int woff = (o0 + lq) * NCH + grp * 8;

    f32x4 acc[2];
    acc[0] = (f32x4){0.f, 0.f, 0.f, 0.f};
    acc[1] = acc[0];
#pragma unroll
    for (int kc = 0; kc < 8; ++kc) {
        const s16x8 ah = load8(Wh + woff + kc * 32);
        const s16x8 al = load8(Wl + woff + kc * 32);
#pragma unroll
        for (int nt = 0; nt < 2; ++nt) {
            const int n = n0 + nt * 16 + lq;
            const float inv = inv_lds[kc * 32 + nt * 16 + lq];
            const size_t base = (size_t)n * NCH + kc * 32 + grp * 8;
            const s16x8 r0 = load8(Opb + base);
            const s16x8 r1 = load8(Opb + (size_t)1 * NPOS * NCH + base);
            const s16x8 r2 = load8(Opb + (size_t)2 * NPOS * NCH + base);
            const s16x8 r3 = load8(Opb + (size_t)3 * NPOS * NCH + base);
            ushort hb[8], lb[8];
#pragma unroll
            for (int e = 0; e < 8; ++e) {
                const float f = (bfval((ushort)r0[e]) + bfval((ushort)r1[e]) +
                                 bfval((ushort)r2[e]) + bfval((ushort)r3[e])) * inv;
                hb[e] = bfbits(f);
                lb[e] = bfbits(f - bfval(hb[e]));
            }
            const s16x8 bh = __builtin_bit_cast(s16x8,
                (u32x4){(uint)hb[0] | ((uint)hb[1] << 16), (uint)hb[2] | ((uint)hb[3] << 16),
                        (uint)hb[4] | ((uint)hb[5] << 16), (uint)hb[6] | ((uint)hb[7] << 16)});
            const s16x8 bl = __builtin_bit_cast(s16x8,
                (u32x4){(uint)lb[0] | ((uint)lb[1] << 16), (uint)lb[2] | ((uint)lb[3] << 16),
                        (uint)lb[4] | ((uint)lb[5] << 16), (uint)lb[6] | ((uint)lb[7] << 16)});
            acc[nt] = __builtin_amdgcn_mfma_f32_16x16x32_bf16(ah, bh, acc[nt], 0, 0, 0);
            acc[nt] = __builtin_amdgcn_mfma_f32_16x16x32_bf16(ah, bl, acc[nt], 0, 0, 0);
            acc[nt] = __builtin_amdgcn_mfma_f32_16x16x32_bf16(al, bh, acc[nt], 0, 0, 0);
        }
    }
    const f32x4 b4 = *(const f32x4*)(bias + o0 + grp * 4);
#pragma unroll
    for (int nt = 0; nt < 2; ++nt) {
        const int n = n0 + nt * 16 + lq;
#pragma unroll
        for (int r = 0; r < 4; ++r)
            Y[(o0 + grp * 4 + r) * NPOS + n] = acc[nt][r] + b4[r];
    }
}

extern "C" void kernel_launch(void* const* d_in, const int* in_sizes, int n_in,
                              void* d_out, int out_size, void* d_ws, size_t ws_size,
                              hipStream_t stream) {
    const float* x1 = (const float*)d_in[0];
    const float* x2 = (const float*)d_in[1];
    const float* Wq = (const float*)d_in[2];
    const float* Wk = (const float*)d_in[3];
    const float* Wv = (const float*)d_in[4];
    const float* Wp = (const float*)d_in[5];
    const float* bp = (const float*)d_in[6];
    float* out = (float*)d_out;

    const size_t MB = 1u << 20;
    char* wsc = (char*)d_ws;
    ushort* xt1h = (ushort*)(wsc + 0 * MB);
    ushort* xt1l = (ushort*)(wsc + 2 * MB);
    ushort* xt2h = (ushort*)(wsc + 4 * MB);
    ushort* xt2l = (ushort*)(wsc + 6 * MB);
    ushort* qt   = (ushort*)(wsc + 8 * MB);
    ushort* kt   = (ushort*)(wsc + 10 * MB);
    ushort* vt   = (ushort*)(wsc + 12 * MB);
    ushort* wsp  = (ushort*)(wsc + 14 * MB);   // [4][2][65536] bf16
    float*  Ml   = (float*)(wsc + 15 * MB);    // [4][8][4096] f32 (l)
    ushort* Opb  = (ushort*)(wsc + 0 * MB);    // [4][4096][256] bf16 (over xt*)

    const float qscale = (float)(0.17677669529663687 * 1.4426950408889634);

    convert_kernel<<<dim3(64, 4, 3), 256, 0, stream>>>(
        x1, x2, Wq, Wk, Wv, Wp, xt1h, xt1l, xt2h, xt2l, wsp, qscale);

    gemm_qkv_kernel<<<dim3(128, 12), 256, 0, stream>>>(
        wsp, xt1h, xt1l, xt2h, xt2l, qt, kt, vt);

    attn_mfma_kernel<<<1024, 256, 0, stream>>>(qt, kt, vt, Opb, Ml);

    ushort* wph = wsp + 393216;
    ushort* wpl = wsp + 458752;
    gemm_out_kernel<<<dim3(128, 4), 256, 0, stream>>>(
        wph, wpl, Opb, Ml, bp, out);
}

// Round 12
// 102.040 us; speedup vs baseline: 1.0276x; 1.0276x over previous
//
#include <hip/hip_runtime.h>

#define NPOS 4096      // H*W
#define NCH  256       // channels
#define HD   32        // head dim
#define KB   128       // keys per attention step
#define NSPLIT 4
#define SPLIT_KEYS (NPOS / NSPLIT)
#define NSTEP (SPLIT_KEYS / KB)

typedef float f32x4  __attribute__((ext_vector_type(4)));
typedef float f32x16 __attribute__((ext_vector_type(16)));
typedef short s16x8  __attribute__((ext_vector_type(8)));
typedef uint  u32x2  __attribute__((ext_vector_type(2)));
typedef uint  u32x4  __attribute__((ext_vector_type(4)));
typedef int   i32x2  __attribute__((ext_vector_type(2)));

static __device__ __forceinline__ s16x8 load8(const ushort* p) {
    return *(const s16x8*)p;
}
static __device__ __forceinline__ ushort bfbits(float x) {
    __bf16 b = (__bf16)x;
    return __builtin_bit_cast(unsigned short, b);
}
static __device__ __forceinline__ float bfval(ushort u) {
    uint x = (uint)u << 16;
    return __builtin_bit_cast(float, x);
}
static __device__ __forceinline__ uint pk2(float a, float b) {
    return (uint)bfbits(a) | ((uint)bfbits(b) << 16);
}
// permlane32_swap: a -> (a_lo, b_lo-from-partner), b -> (a_hi, b_hi)
static __device__ __forceinline__ void plswap(uint& a, uint& b) {
    i32x2 r = __builtin_amdgcn_permlane32_swap((int)a, (int)b, false, false);
    a = (uint)r[0];
    b = (uint)r[1];
}

// ---------------- fused input conversion ----------------
// z=0: x1 -> xt1 hi/lo [4096][256]; z=1: x2 -> xt2; z=2: W matrices -> wsp.
__global__ __launch_bounds__(256) void convert_kernel(
    const float* __restrict__ x1, const float* __restrict__ x2,
    const float* __restrict__ Wq, const float* __restrict__ Wk,
    const float* __restrict__ Wv, const float* __restrict__ Wp,
    ushort* __restrict__ xt1h, ushort* __restrict__ xt1l,
    ushort* __restrict__ xt2h, ushort* __restrict__ xt2l,
    ushort* __restrict__ wsp, float qscale)
{
    if (blockIdx.z == 2) {
        const int m = blockIdx.y;
        const float* src = m == 0 ? Wq : m == 1 ? Wk : m == 2 ? Wv : Wp;
        const float sc = m == 0 ? qscale : 1.f;
        const int idx = (blockIdx.x * 256 + threadIdx.x) * 4;
        f32x4 w = *(const f32x4*)(src + idx);
        w *= sc;
        ushort h[4], l[4];
#pragma unroll
        for (int i = 0; i < 4; ++i) {
            h[i] = bfbits(w[i]);
            l[i] = bfbits(w[i] - bfval(h[i]));
        }
        ushort* H = wsp + m * 2 * 65536;
        *(u32x2*)(H + idx)         = (u32x2){(uint)h[0] | ((uint)h[1] << 16),
                                             (uint)h[2] | ((uint)h[3] << 16)};
        *(u32x2*)(H + 65536 + idx) = (u32x2){(uint)l[0] | ((uint)l[1] << 16),
                                             (uint)l[2] | ((uint)l[3] << 16)};
        return;
    }
    __shared__ float tile[64][65];
    const float* X = blockIdx.z ? x2 : x1;
    ushort* Hd = blockIdx.z ? xt2h : xt1h;
    ushort* Ld = blockIdx.z ? xt2l : xt1l;
    const int n0 = blockIdx.x * 64, c0 = blockIdx.y * 64;
    const int tj = threadIdx.x & 63, ti = threadIdx.x >> 6;
#pragma unroll
    for (int r = 0; r < 16; ++r) {
        int i = r * 4 + ti;
        tile[i][tj] = X[(c0 + i) * NPOS + n0 + tj];
    }
    __syncthreads();
#pragma unroll
    for (int r = 0; r < 16; ++r) {
        int i = r * 4 + ti;                       // n offset
        float v = tile[tj][i];                    // X[c0+tj][n0+i]
        ushort h = bfbits(v);
        ushort l = bfbits(v - bfval(h));
        Hd[(n0 + i) * NCH + c0 + tj] = h;
        Ld[(n0 + i) * NCH + c0 + tj] = l;
    }
}

// ---------------- fused QKV projection (bf16x3 MFMA) ----------------
// grid (128, 12): y>>2 = m (0 Q from x1, 1 K from x2, 2 V from x2), y&3 = ob.
__global__ __launch_bounds__(256) void gemm_qkv_kernel(
    const ushort* __restrict__ wsp,
    const ushort* __restrict__ x1h, const ushort* __restrict__ x1l,
    const ushort* __restrict__ x2h, const ushort* __restrict__ x2l,
    ushort* __restrict__ qt, ushort* __restrict__ kt, ushort* __restrict__ vt)
{
    const int m  = blockIdx.y >> 2;
    const int ob = blockIdx.y & 3;
    const ushort* Wh = wsp + m * 131072;
    const ushort* Wl = Wh + 65536;
    const ushort* Bh = (m == 0) ? x1h : x2h;
    const ushort* Bl = (m == 0) ? x1l : x2l;

    const int wid = threadIdx.x >> 6, lane = threadIdx.x & 63;
    const int lq = lane & 15, grp = lane >> 4;
    const int o0 = ob * 64 + wid * 16;
    const int n0 = blockIdx.x * 32;
    const int woff = (o0 + lq) * NCH + grp * 8;
    const int boff = (n0 + lq) * NCH + grp * 8;

    f32x4 acc[2];
    acc[0] = (f32x4){0.f, 0.f, 0.f, 0.f};
    acc[1] = acc[0];
#pragma unroll
    for (int kc = 0; kc < 8; ++kc) {
        const s16x8 ah = load8(Wh + woff + kc * 32);
        const s16x8 al = load8(Wl + woff + kc * 32);
#pragma unroll
        for (int nt = 0; nt < 2; ++nt) {
            const s16x8 bh = load8(Bh + boff + nt * 16 * NCH + kc * 32);
            const s16x8 bl = load8(Bl + boff + nt * 16 * NCH + kc * 32);
            acc[nt] = __builtin_amdgcn_mfma_f32_16x16x32_bf16(ah, bh, acc[nt], 0, 0, 0);
            acc[nt] = __builtin_amdgcn_mfma_f32_16x16x32_bf16(ah, bl, acc[nt], 0, 0, 0);
            acc[nt] = __builtin_amdgcn_mfma_f32_16x16x32_bf16(al, bh, acc[nt], 0, 0, 0);
        }
    }
    if (m < 2) {
        ushort* Y = m ? kt : qt;
        const int head = o0 >> 5, d0 = (o0 & 31) + grp * 4;
#pragma unroll
        for (int nt = 0; nt < 2; ++nt) {
            const int n = n0 + nt * 16 + lq;
            *(u32x2*)(Y + head * (NPOS * HD) + n * HD + d0) =
                (u32x2){pk2(acc[nt][0], acc[nt][1]), pk2(acc[nt][2], acc[nt][3])};
        }
    } else {
#pragma unroll
        for (int nt = 0; nt < 2; ++nt) {
            const int n = n0 + nt * 16 + lq;
#pragma unroll
            for (int r = 0; r < 4; ++r)
                vt[(o0 + grp * 4 + r) * NPOS + n] = bfbits(acc[nt][r]);
        }
    }
}

// ---- MFMA flash attention: 32x32, no max, LDS dbuf (1 barrier/step) ----
// grid 1024: s = bid>>8, h = bid&7, qblk = (bid&255)>>3. KB=128, 8 steps.
__global__ __launch_bounds__(256) void attn_mfma_kernel(
    const ushort* __restrict__ Qt,   // [8][4096][32] bf16, pre-scaled s*log2e
    const ushort* __restrict__ Kt,   // [8][4096][32] bf16
    const ushort* __restrict__ Vt,   // [8][32][4096] bf16
    ushort* __restrict__ Opb,        // [4][4096][256] bf16 unnormalized
    float* __restrict__ Ml)          // [4][8][4096] f32 (l)
{
    __shared__ __align__(16) ushort lds[18944];  // K0@0 K1@5120 V0@10240 V1@14592
    const int bid  = blockIdx.x;
    const int s    = bid >> 8;
    const int h    = bid & 7;
    const int qblk = (bid & 255) >> 3;   // 0..31
    const int tid  = threadIdx.x;
    const int wid  = tid >> 6;
    const int lane = tid & 63;
    const int l31  = lane & 31;
    const int hi   = lane >> 5;
    const int q0   = qblk * 128 + wid * 32;
    const int k0   = s * SPLIT_KEYS;
    const int hq   = h * (NPOS * HD);

    s16x8 qf[2];
#pragma unroll
    for (int kh = 0; kh < 2; ++kh)
        qf[kh] = load8(Qt + hq + (q0 + l31) * HD + kh * 16 + hi * 8);

    const int kr0 = tid >> 2, kc0 = tid & 3;
    const ushort* kS = Kt + hq + kr0 * HD + kc0 * 8;
    const int kdst0 = kr0 * 40 + ((kc0 ^ ((kr0 >> 3) & 3)) & 3) * 8;
    const int kdst1 = kdst0 + 64 * 40;

    const int vr0 = tid >> 4, vc0 = tid & 15;
    const ushort* vS = Vt + h * (HD * NPOS) + vr0 * NPOS + vc0 * 8;
    const int vdst0 = vr0 * 136 + ((vc0 ^ ((vr0 >> 3) & 3)) & 15) * 8;
    const int vdst1 = (vr0 + 16) * 136 +
                      ((vc0 ^ (((vr0 + 16) >> 3) & 3)) & 15) * 8;

    const int kx = l31 >> 3;

    s16x8 onesf;
#pragma unroll
    for (int i = 0; i < 8; ++i) onesf[i] = (short)0x3F80;

    f32x16 oacc = {};
    f32x16 accl = {};

    // prologue: tile0 -> buf0; prefetch tile1 into regs
    *(s16x8*)(lds + kdst0)         = load8(kS + (size_t)k0 * HD);
    *(s16x8*)(lds + kdst1)         = load8(kS + (size_t)k0 * HD + 64 * HD);
    *(s16x8*)(lds + 10240 + vdst0) = load8(vS + k0);
    *(s16x8*)(lds + 10240 + vdst1) = load8(vS + k0 + 16 * NPOS);
    int m1 = (NSTEP > 1) ? k0 + KB : k0;
    s16x8 kra = load8(kS + (size_t)m1 * HD);
    s16x8 krb = load8(kS + (size_t)m1 * HD + 64 * HD);
    s16x8 vra = load8(vS + m1);
    s16x8 vrb = load8(vS + m1 + 16 * NPOS);
    __syncthreads();

    for (int step = 0; step < NSTEP; ++step) {
        const int cur = step & 1;
        ushort* const Kb = lds + cur * 5120;
        ushort* const Vb = lds + 10240 + cur * 4352;

        // write prefetched tile (step+1) into the other buffer
        {
            ushort* const Kn = lds + (cur ^ 1) * 5120;
            ushort* const Vn = lds + 10240 + (cur ^ 1) * 4352;
            *(s16x8*)(Kn + kdst0) = kra;
            *(s16x8*)(Kn + kdst1) = krb;
            *(s16x8*)(Vn + vdst0) = vra;
            *(s16x8*)(Vn + vdst1) = vrb;
        }
        // issue loads for tile step+2
        const int mn = (step + 2 < NSTEP) ? k0 + (step + 2) * KB : k0;
        kra = load8(kS + (size_t)mn * HD);
        krb = load8(kS + (size_t)mn * HD + 64 * HD);
        vra = load8(vS + mn);
        vrb = load8(vS + mn + 16 * NPOS);

#pragma unroll
        for (int t = 0; t < 4; ++t) {
            const int krow = (t * 32 + l31) * 40;
            const s16x8 kfa = *(const s16x8*)(Kb + krow + ((hi ^ kx) & 3) * 8);
            const s16x8 kfb = *(const s16x8*)(Kb + krow + (((2 + hi) ^ kx) & 3) * 8);
            f32x16 st = {};
            __builtin_amdgcn_s_setprio(1);
            st = __builtin_amdgcn_mfma_f32_32x32x16_bf16(kfa, qf[0], st, 0, 0, 0);
            st = __builtin_amdgcn_mfma_f32_32x32x16_bf16(kfb, qf[1], st, 0, 0, 0);
            __builtin_amdgcn_s_setprio(0);

            const s16x8 vf0 = *(const s16x8*)(Vb + l31 * 136 +
                                              (((t * 4 + hi) ^ kx) & 15) * 8);
            const s16x8 vf1 = *(const s16x8*)(Vb + l31 * 136 +
                                              (((t * 4 + 2 + hi) ^ kx) & 15) * 8);

            uint w[4], w2[4];
#pragma unroll
            for (int g = 0; g < 4; ++g) {
                const float p0 = __builtin_amdgcn_exp2f(st[4 * g + 0]);
                const float p1 = __builtin_amdgcn_exp2f(st[4 * g + 1]);
                const float p2 = __builtin_amdgcn_exp2f(st[4 * g + 2]);
                const float p3 = __builtin_amdgcn_exp2f(st[4 * g + 3]);
                w[g]  = pk2(p0, p1);
                w2[g] = pk2(p2, p3);
            }
            uint a0 = w[0],  c0 = w[1];  plswap(a0, c0);
            uint a1 = w2[0], c1 = w2[1]; plswap(a1, c1);
            const s16x8 pfA = __builtin_bit_cast(s16x8, (u32x4){a0, a1, c0, c1});
            uint b0 = w[2],  d0 = w[3];  plswap(b0, d0);
            uint b1 = w2[2], d1 = w2[3]; plswap(b1, d1);
            const s16x8 pfB = __builtin_bit_cast(s16x8, (u32x4){b0, b1, d0, d1});

            __builtin_amdgcn_s_setprio(1);
            oacc = __builtin_amdgcn_mfma_f32_32x32x16_bf16(vf0, pfA, oacc, 0, 0, 0);
            oacc = __builtin_amdgcn_mfma_f32_32x32x16_bf16(vf1, pfB, oacc, 0, 0, 0);
            accl = __builtin_amdgcn_mfma_f32_32x32x16_bf16(onesf, pfA, accl, 0, 0, 0);
            accl = __builtin_amdgcn_mfma_f32_32x32x16_bf16(onesf, pfB, accl, 0, 0, 0);
            __builtin_amdgcn_s_setprio(0);
        }

        __syncthreads();
    }

    // --- write unnormalized partials (bf16, n-major) + l ---
    const int n = q0 + l31;
    ushort* Ops = Opb + (size_t)s * (NPOS * NCH) + n * NCH + h * HD;
#pragma unroll
    for (int g = 0; g < 4; ++g) {
        *(u32x2*)(Ops + g * 8 + hi * 4) =
            (u32x2){pk2(oacc[4 * g + 0], oacc[4 * g + 1]),
                    pk2(oacc[4 * g + 2], oacc[4 * g + 3])};
    }
    if (lane < 32)
        Ml[(s * 8 + h) * NPOS + n] = accl[0];
}

// split-K combine + hi/lo conversion: Opb[4][n][c] bf16 -> FT hi/lo bf16.
__global__ __launch_bounds__(256) void combine_kernel(
    const ushort* __restrict__ Opb, const float* __restrict__ Ml,
    ushort* __restrict__ FH, ushort* __restrict__ FL)
{
    const int n = blockIdx.x * 4 + (threadIdx.x >> 6);
    const int c = (threadIdx.x & 63) * 4;
    const int h = c >> 5;
    float l = 0.f;
#pragma unroll
    for (int s = 0; s < NSPLIT; ++s)
        l += Ml[(s * 8 + h) * NPOS + n];
    const float inv = 1.f / l;

    float sum[4] = {0.f, 0.f, 0.f, 0.f};
#pragma unroll
    for (int s = 0; s < NSPLIT; ++s) {
        const u32x2 raw = *(const u32x2*)(Opb + (size_t)s * (NPOS * NCH) +
                                          n * NCH + c);
        sum[0] += bfval((ushort)(raw[0] & 0xFFFF));
        sum[1] += bfval((ushort)(raw[0] >> 16));
        sum[2] += bfval((ushort)(raw[1] & 0xFFFF));
        sum[3] += bfval((ushort)(raw[1] >> 16));
    }
    ushort hb[4], lb[4];
#pragma unroll
    for (int i = 0; i < 4; ++i) {
        float f = sum[i] * inv;
        hb[i] = bfbits(f);
        lb[i] = bfbits(f - bfval(hb[i]));
    }
    *(u32x2*)(FH + n * NCH + c) = (u32x2){(uint)hb[0] | ((uint)hb[1] << 16),
                                          (uint)hb[2] | ((uint)hb[3] << 16)};
    *(u32x2*)(FL + n * NCH + c) = (u32x2){(uint)lb[0] | ((uint)lb[1] << 16),
                                          (uint)lb[2] | ((uint)lb[3] << 16)};
}

// Output projection: C = Wp @ F + bias, f32 out [256][4096].
__global__ __launch_bounds__(256) void gemm_out_kernel(
    const ushort* __restrict__ Wh, const ushort* __restrict__ Wl,
    const ushort* __restrict__ Bh, const ushort* __restrict__ Bl,
    const float* __restrict__ bias, float* __restrict__ Y)
{
    const int wid = threadIdx.x >> 6, lane = threadIdx.x & 63;
    const int lq = lane & 15, grp = lane >> 4;
    const int o0 = blockIdx.y * 64 + wid * 16;
    const int n0 = blockIdx.x * 32;
    const int woff = (o0 + lq) * NCH + grp * 8;
    const int boff = (n0 + lq) * NCH + grp * 8;

    f32x4 acc[2];
    acc[0] = (f32x4){0.f, 0.f, 0.f, 0.f};
    acc[1] = acc[0];
#pragma unroll
    for (int kc = 0; kc < 8; ++kc) {
        const s16x8 ah = load8(Wh + woff + kc * 32);
        const s16x8 al = load8(Wl + woff + kc * 32);
#pragma unroll
        for (int nt = 0; nt < 2; ++nt) {
            const s16x8 bh = load8(Bh + boff + nt * 16 * NCH + kc * 32);
            const s16x8 bl = load8(Bl + boff + nt * 16 * NCH + kc * 32);
            acc[nt] = __builtin_amdgcn_mfma_f32_16x16x32_bf16(ah, bh, acc[nt], 0, 0, 0);
            acc[nt] = __builtin_amdgcn_mfma_f32_16x16x32_bf16(ah, bl, acc[nt], 0, 0, 0);
            acc[nt] = __builtin_amdgcn_mfma_f32_16x16x32_bf16(al, bh, acc[nt], 0, 0, 0);
        }
    }
    const f32x4 b4 = *(const f32x4*)(bias + o0 + grp * 4);
#pragma unroll
    for (int nt = 0; nt < 2; ++nt) {
        const int n = n0 + nt * 16 + lq;
#pragma unroll
        for (int r = 0; r < 4; ++r)
            Y[(o0 + grp * 4 + r) * NPOS + n] = acc[nt][r] + b4[r];
    }
}

extern "C" void kernel_launch(void* const* d_in, const int* in_sizes, int n_in,
                              void* d_out, int out_size, void* d_ws, size_t ws_size,
                              hipStream_t stream) {
    const float* x1 = (const float*)d_in[0];
    const float* x2 = (const float*)d_in[1];
    const float* Wq = (const float*)d_in[2];
    const float* Wk = (const float*)d_in[3];
    const float* Wv = (const float*)d_in[4];
    const float* Wp = (const float*)d_in[5];
    const float* bp = (const float*)d_in[6];
    float* out = (float*)d_out;

    const size_t MB = 1u << 20;
    char* wsc = (char*)d_ws;
    ushort* xt1h = (ushort*)(wsc + 0 * MB);
    ushort* xt1l = (ushort*)(wsc + 2 * MB);
    ushort* xt2h = (ushort*)(wsc + 4 * MB);
    ushort* xt2l = (ushort*)(wsc + 6 * MB);
    ushort* qt   = (ushort*)(wsc + 8 * MB);
    ushort* kt   = (ushort*)(wsc + 10 * MB);
    ushort* vt   = (ushort*)(wsc + 12 * MB);
    ushort* wsp  = (ushort*)(wsc + 14 * MB);   // [4][2][65536] bf16
    float*  Ml   = (float*)(wsc + 15 * MB);    // [4][8][4096] f32 (l)
    ushort* Opb  = (ushort*)(wsc + 0 * MB);    // [4][4096][256] bf16 (over xt*)
    ushort* fth  = (ushort*)(wsc + 8 * MB);    // over qt
    ushort* ftl  = (ushort*)(wsc + 10 * MB);   // over kt

    const float qscale = (float)(0.17677669529663687 * 1.4426950408889634);

    convert_kernel<<<dim3(64, 4, 3), 256, 0, stream>>>(
        x1, x2, Wq, Wk, Wv, Wp, xt1h, xt1l, xt2h, xt2l, wsp, qscale);

    gemm_qkv_kernel<<<dim3(128, 12), 256, 0, stream>>>(
        wsp, xt1h, xt1l, xt2h, xt2l, qt, kt, vt);

    attn_mfma_kernel<<<1024, 256, 0, stream>>>(qt, kt, vt, Opb, Ml);

    combine_kernel<<<1024, 256, 0, stream>>>(Opb, Ml, fth, ftl);

    ushort* wph = wsp + 393216;
    ushort* wpl = wsp + 458752;
    gemm_out_kernel<<<dim3(128, 4), 256, 0, stream>>>(
        wph, wpl, fth, ftl, bp, out);
}

// Round 13
// 75.576 us; speedup vs baseline: 1.3874x; 1.3502x over previous
//
#include <hip/hip_runtime.h>

#define NPOS 4096      // H*W
#define NCH  256       // channels
#define HD   32        // head dim
#define KB   128       // keys per attention step
#define NSPLIT 4
#define SPLIT_KEYS (NPOS / NSPLIT)
#define NSTEP (SPLIT_KEYS / KB)

// fragment-tiled layout: element (row o, col c) of a [R][256] bf16 matrix at
// ushort offset TOFF(o,c); a wave's (o-tile, kc) fragment = contiguous 1KB.
#define TOFF(o, c) (((((o) >> 4) * 8 + ((c) >> 5)) * 64 + \
                     ((((c) >> 3) & 3) * 16) + ((o) & 15)) * 8 + ((c) & 7))

typedef float f32x4  __attribute__((ext_vector_type(4)));
typedef float f32x16 __attribute__((ext_vector_type(16)));
typedef short s16x8  __attribute__((ext_vector_type(8)));
typedef uint  u32x2  __attribute__((ext_vector_type(2)));
typedef uint  u32x4  __attribute__((ext_vector_type(4)));
typedef int   i32x2  __attribute__((ext_vector_type(2)));

static __device__ __forceinline__ s16x8 load8(const ushort* p) {
    return *(const s16x8*)p;
}
static __device__ __forceinline__ ushort bfbits(float x) {
    __bf16 b = (__bf16)x;
    return __builtin_bit_cast(unsigned short, b);
}
static __device__ __forceinline__ float bfval(ushort u) {
    uint x = (uint)u << 16;
    return __builtin_bit_cast(float, x);
}
static __device__ __forceinline__ uint pk2(float a, float b) {
    return (uint)bfbits(a) | ((uint)bfbits(b) << 16);
}
// permlane32_swap: a -> (a_lo, b_lo-from-partner), b -> (a_hi, b_hi)
static __device__ __forceinline__ void plswap(uint& a, uint& b) {
    i32x2 r = __builtin_amdgcn_permlane32_swap((int)a, (int)b, false, false);
    a = (uint)r[0];
    b = (uint)r[1];
}

// ---------------- fused input conversion (tiled outputs) ----------------
// z=0: x1 -> xt1 hi/lo tiled; z=1: x2 -> xt2; z=2: W matrices -> wsp tiled.
__global__ __launch_bounds__(256) void convert_kernel(
    const float* __restrict__ x1, const float* __restrict__ x2,
    const float* __restrict__ Wq, const float* __restrict__ Wk,
    const float* __restrict__ Wv, const float* __restrict__ Wp,
    ushort* __restrict__ xt1h, ushort* __restrict__ xt1l,
    ushort* __restrict__ xt2h, ushort* __restrict__ xt2l,
    ushort* __restrict__ wsp, float qscale)
{
    if (blockIdx.z == 2) {
        const int m = blockIdx.y;
        const float* src = m == 0 ? Wq : m == 1 ? Wk : m == 2 ? Wv : Wp;
        const float sc = m == 0 ? qscale : 1.f;
        const int idx = (blockIdx.x * 256 + threadIdx.x) * 4;
        const int o = idx >> 8, c0 = idx & 255;
        f32x4 w = *(const f32x4*)(src + idx);
        w *= sc;
        ushort h[4], l[4];
#pragma unroll
        for (int i = 0; i < 4; ++i) {
            h[i] = bfbits(w[i]);
            l[i] = bfbits(w[i] - bfval(h[i]));
        }
        ushort* H = wsp + m * 2 * 65536;
        const int off = TOFF(o, c0);
        *(u32x2*)(H + off)         = (u32x2){(uint)h[0] | ((uint)h[1] << 16),
                                             (uint)h[2] | ((uint)h[3] << 16)};
        *(u32x2*)(H + 65536 + off) = (u32x2){(uint)l[0] | ((uint)l[1] << 16),
                                             (uint)l[2] | ((uint)l[3] << 16)};
        return;
    }
    __shared__ float tile[64][65];
    const float* X = blockIdx.z ? x2 : x1;
    ushort* Hd = blockIdx.z ? xt2h : xt1h;
    ushort* Ld = blockIdx.z ? xt2l : xt1l;
    const int n0 = blockIdx.x * 64, c0 = blockIdx.y * 64;
    const int tj = threadIdx.x & 63, ti = threadIdx.x >> 6;
#pragma unroll
    for (int r = 0; r < 16; ++r) {
        int i = r * 4 + ti;
        tile[i][tj] = X[(c0 + i) * NPOS + n0 + tj];
    }
    __syncthreads();
#pragma unroll
    for (int r = 0; r < 16; ++r) {
        int i = r * 4 + ti;                       // n offset
        float v = tile[tj][i];                    // X[c0+tj][n0+i]
        ushort h = bfbits(v);
        ushort l = bfbits(v - bfval(h));
        const int off = TOFF(n0 + i, c0 + tj);
        Hd[off] = h;
        Ld[off] = l;
    }
}

// ---------------- fused QKV projection (bf16x3 MFMA, tiled operands) ------
// grid (128, 12): y>>2 = m (0 Q from x1, 1 K from x2, 2 V from x2), y&3 = ob.
// All fragment loads are base + lane*8 (contiguous 1KB per wave).
__global__ __launch_bounds__(256) void gemm_qkv_kernel(
    const ushort* __restrict__ wsp,
    const ushort* __restrict__ x1h, const ushort* __restrict__ x1l,
    const ushort* __restrict__ x2h, const ushort* __restrict__ x2l,
    ushort* __restrict__ qt, ushort* __restrict__ kt, ushort* __restrict__ vt)
{
    const int m  = blockIdx.y >> 2;
    const int ob = blockIdx.y & 3;
    const ushort* Wh = wsp + m * 131072;
    const ushort* Wl = Wh + 65536;
    const ushort* Bh = (m == 0) ? x1h : x2h;
    const ushort* Bl = (m == 0) ? x1l : x2l;

    const int wid = threadIdx.x >> 6, lane = threadIdx.x & 63;
    const int lq = lane & 15, grp = lane >> 4;
    const int o0 = ob * 64 + wid * 16;
    const int n0 = blockIdx.x * 32;
    const int To = o0 >> 4;          // W row-tile
    const int Tn = n0 >> 4;          // X row-tile base

    f32x4 acc[2];
    acc[0] = (f32x4){0.f, 0.f, 0.f, 0.f};
    acc[1] = acc[0];
#pragma unroll
    for (int kc = 0; kc < 8; ++kc) {
        const s16x8 ah = load8(Wh + ((To * 8 + kc) * 64 + lane) * 8);
        const s16x8 al = load8(Wl + ((To * 8 + kc) * 64 + lane) * 8);
#pragma unroll
        for (int nt = 0; nt < 2; ++nt) {
            const s16x8 bh = load8(Bh + (((Tn + nt) * 8 + kc) * 64 + lane) * 8);
            const s16x8 bl = load8(Bl + (((Tn + nt) * 8 + kc) * 64 + lane) * 8);
            acc[nt] = __builtin_amdgcn_mfma_f32_16x16x32_bf16(ah, bh, acc[nt], 0, 0, 0);
            acc[nt] = __builtin_amdgcn_mfma_f32_16x16x32_bf16(ah, bl, acc[nt], 0, 0, 0);
            acc[nt] = __builtin_amdgcn_mfma_f32_16x16x32_bf16(al, bh, acc[nt], 0, 0, 0);
        }
    }
    if (m < 2) {
        ushort* Y = m ? kt : qt;
        const int head = o0 >> 5, d0 = (o0 & 31) + grp * 4;
#pragma unroll
        for (int nt = 0; nt < 2; ++nt) {
            const int n = n0 + nt * 16 + lq;
            *(u32x2*)(Y + head * (NPOS * HD) + n * HD + d0) =
                (u32x2){pk2(acc[nt][0], acc[nt][1]), pk2(acc[nt][2], acc[nt][3])};
        }
    } else {
#pragma unroll
        for (int nt = 0; nt < 2; ++nt) {
            const int n = n0 + nt * 16 + lq;
#pragma unroll
            for (int r = 0; r < 4; ++r)
                vt[(o0 + grp * 4 + r) * NPOS + n] = bfbits(acc[nt][r]);
        }
    }
}

// ---- MFMA flash attention: 32x32, no max, LDS dbuf (1 barrier/step) ----
// grid 1024: s = bid>>8, h = bid&7, qblk = (bid&255)>>3. KB=128, 8 steps.
__global__ __launch_bounds__(256) void attn_mfma_kernel(
    const ushort* __restrict__ Qt,   // [8][4096][32] bf16, pre-scaled s*log2e
    const ushort* __restrict__ Kt,   // [8][4096][32] bf16
    const ushort* __restrict__ Vt,   // [8][32][4096] bf16
    ushort* __restrict__ Opb,        // [4][4096][256] bf16 unnormalized
    float* __restrict__ Ml)          // [4][8][4096] f32 (l)
{
    __shared__ __align__(16) ushort lds[18944];  // K0@0 K1@5120 V0@10240 V1@14592
    const int bid  = blockIdx.x;
    const int s    = bid >> 8;
    const int h    = bid & 7;
    const int qblk = (bid & 255) >> 3;   // 0..31
    const int tid  = threadIdx.x;
    const int wid  = tid >> 6;
    const int lane = tid & 63;
    const int l31  = lane & 31;
    const int hi   = lane >> 5;
    const int q0   = qblk * 128 + wid * 32;
    const int k0   = s * SPLIT_KEYS;
    const int hq   = h * (NPOS * HD);

    s16x8 qf[2];
#pragma unroll
    for (int kh = 0; kh < 2; ++kh)
        qf[kh] = load8(Qt + hq + (q0 + l31) * HD + kh * 16 + hi * 8);

    const int kr0 = tid >> 2, kc0 = tid & 3;
    const ushort* kS = Kt + hq + kr0 * HD + kc0 * 8;
    const int kdst0 = kr0 * 40 + ((kc0 ^ ((kr0 >> 3) & 3)) & 3) * 8;
    const int kdst1 = kdst0 + 64 * 40;

    const int vr0 = tid >> 4, vc0 = tid & 15;
    const ushort* vS = Vt + h * (HD * NPOS) + vr0 * NPOS + vc0 * 8;
    const int vdst0 = vr0 * 136 + ((vc0 ^ ((vr0 >> 3) & 3)) & 15) * 8;
    const int vdst1 = (vr0 + 16) * 136 +
                      ((vc0 ^ (((vr0 + 16) >> 3) & 3)) & 15) * 8;

    const int kx = l31 >> 3;

    s16x8 onesf;
#pragma unroll
    for (int i = 0; i < 8; ++i) onesf[i] = (short)0x3F80;

    f32x16 oacc = {};
    f32x16 accl = {};

    // prologue: tile0 -> buf0; prefetch tile1 into regs
    *(s16x8*)(lds + kdst0)         = load8(kS + (size_t)k0 * HD);
    *(s16x8*)(lds + kdst1)         = load8(kS + (size_t)k0 * HD + 64 * HD);
    *(s16x8*)(lds + 10240 + vdst0) = load8(vS + k0);
    *(s16x8*)(lds + 10240 + vdst1) = load8(vS + k0 + 16 * NPOS);
    int m1 = (NSTEP > 1) ? k0 + KB : k0;
    s16x8 kra = load8(kS + (size_t)m1 * HD);
    s16x8 krb = load8(kS + (size_t)m1 * HD + 64 * HD);
    s16x8 vra = load8(vS + m1);
    s16x8 vrb = load8(vS + m1 + 16 * NPOS);
    __syncthreads();

    for (int step = 0; step < NSTEP; ++step) {
        const int cur = step & 1;
        ushort* const Kb = lds + cur * 5120;
        ushort* const Vb = lds + 10240 + cur * 4352;

        // write prefetched tile (step+1) into the other buffer
        {
            ushort* const Kn = lds + (cur ^ 1) * 5120;
            ushort* const Vn = lds + 10240 + (cur ^ 1) * 4352;
            *(s16x8*)(Kn + kdst0) = kra;
            *(s16x8*)(Kn + kdst1) = krb;
            *(s16x8*)(Vn + vdst0) = vra;
            *(s16x8*)(Vn + vdst1) = vrb;
        }
        // issue loads for tile step+2
        const int mn = (step + 2 < NSTEP) ? k0 + (step + 2) * KB : k0;
        kra = load8(kS + (size_t)mn * HD);
        krb = load8(kS + (size_t)mn * HD + 64 * HD);
        vra = load8(vS + mn);
        vrb = load8(vS + mn + 16 * NPOS);

#pragma unroll
        for (int t = 0; t < 4; ++t) {
            const int krow = (t * 32 + l31) * 40;
            const s16x8 kfa = *(const s16x8*)(Kb + krow + ((hi ^ kx) & 3) * 8);
            const s16x8 kfb = *(const s16x8*)(Kb + krow + (((2 + hi) ^ kx) & 3) * 8);
            f32x16 st = {};
            __builtin_amdgcn_s_setprio(1);
            st = __builtin_amdgcn_mfma_f32_32x32x16_bf16(kfa, qf[0], st, 0, 0, 0);
            st = __builtin_amdgcn_mfma_f32_32x32x16_bf16(kfb, qf[1], st, 0, 0, 0);
            __builtin_amdgcn_s_setprio(0);

            const s16x8 vf0 = *(const s16x8*)(Vb + l31 * 136 +
                                              (((t * 4 + hi) ^ kx) & 15) * 8);
            const s16x8 vf1 = *(const s16x8*)(Vb + l31 * 136 +
                                              (((t * 4 + 2 + hi) ^ kx) & 15) * 8);

            uint w[4], w2[4];
#pragma unroll
            for (int g = 0; g < 4; ++g) {
                const float p0 = __builtin_amdgcn_exp2f(st[4 * g + 0]);
                const float p1 = __builtin_amdgcn_exp2f(st[4 * g + 1]);
                const float p2 = __builtin_amdgcn_exp2f(st[4 * g + 2]);
                const float p3 = __builtin_amdgcn_exp2f(st[4 * g + 3]);
                w[g]  = pk2(p0, p1);
                w2[g] = pk2(p2, p3);
            }
            uint a0 = w[0],  c0 = w[1];  plswap(a0, c0);
            uint a1 = w2[0], c1 = w2[1]; plswap(a1, c1);
            const s16x8 pfA = __builtin_bit_cast(s16x8, (u32x4){a0, a1, c0, c1});
            uint b0 = w[2],  d0 = w[3];  plswap(b0, d0);
            uint b1 = w2[2], d1 = w2[3]; plswap(b1, d1);
            const s16x8 pfB = __builtin_bit_cast(s16x8, (u32x4){b0, b1, d0, d1});

            __builtin_amdgcn_s_setprio(1);
            oacc = __builtin_amdgcn_mfma_f32_32x32x16_bf16(vf0, pfA, oacc, 0, 0, 0);
            oacc = __builtin_amdgcn_mfma_f32_32x32x16_bf16(vf1, pfB, oacc, 0, 0, 0);
            accl = __builtin_amdgcn_mfma_f32_32x32x16_bf16(onesf, pfA, accl, 0, 0, 0);
            accl = __builtin_amdgcn_mfma_f32_32x32x16_bf16(onesf, pfB, accl, 0, 0, 0);
            __builtin_amdgcn_s_setprio(0);
        }

        __syncthreads();
    }

    // --- write unnormalized partials (bf16, n-major) + l ---
    const int n = q0 + l31;
    ushort* Ops = Opb + (size_t)s * (NPOS * NCH) + n * NCH + h * HD;
#pragma unroll
    for (int g = 0; g < 4; ++g) {
        *(u32x2*)(Ops + g * 8 + hi * 4) =
            (u32x2){pk2(oacc[4 * g + 0], oacc[4 * g + 1]),
                    pk2(oacc[4 * g + 2], oacc[4 * g + 3])};
    }
    if (lane < 32)
        Ml[(s * 8 + h) * NPOS + n] = accl[0];
}

// split-K combine: Opb[4][n][c] bf16 -> FT hi/lo bf16, TILED layout out.
__global__ __launch_bounds__(256) void combine_kernel(
    const ushort* __restrict__ Opb, const float* __restrict__ Ml,
    ushort* __restrict__ FH, ushort* __restrict__ FL)
{
    const int n = blockIdx.x * 4 + (threadIdx.x >> 6);
    const int c = (threadIdx.x & 63) * 4;
    const int h = c >> 5;
    float l = 0.f;
#pragma unroll
    for (int s = 0; s < NSPLIT; ++s)
        l += Ml[(s * 8 + h) * NPOS + n];
    const float inv = 1.f / l;

    float sum[4] = {0.f, 0.f, 0.f, 0.f};
#pragma unroll
    for (int s = 0; s < NSPLIT; ++s) {
        const u32x2 raw = *(const u32x2*)(Opb + (size_t)s * (NPOS * NCH) +
                                          n * NCH + c);
        sum[0] += bfval((ushort)(raw[0] & 0xFFFF));
        sum[1] += bfval((ushort)(raw[0] >> 16));
        sum[2] += bfval((ushort)(raw[1] & 0xFFFF));
        sum[3] += bfval((ushort)(raw[1] >> 16));
    }
    ushort hb[4], lb[4];
#pragma unroll
    for (int i = 0; i < 4; ++i) {
        float f = sum[i] * inv;
        hb[i] = bfbits(f);
        lb[i] = bfbits(f - bfval(hb[i]));
    }
    const int off = TOFF(n, c);
    *(u32x2*)(FH + off) = (u32x2){(uint)hb[0] | ((uint)hb[1] << 16),
                                  (uint)hb[2] | ((uint)hb[3] << 16)};
    *(u32x2*)(FL + off) = (u32x2){(uint)lb[0] | ((uint)lb[1] << 16),
                                  (uint)lb[2] | ((uint)lb[3] << 16)};
}

// Output projection: C = Wp @ F + bias, f32 out [256][4096]. Tiled operands.
__global__ __launch_bounds__(256) void gemm_out_kernel(
    const ushort* __restrict__ Wh, const ushort* __restrict__ Wl,
    const ushort* __restrict__ Bh, const ushort* __restrict__ Bl,
    const float* __restrict__ bias, float* __restrict__ Y)
{
    const int wid = threadIdx.x >> 6, lane = threadIdx.x & 63;
    const int lq = lane & 15, grp = lane >> 4;
    const int o0 = blockIdx.y * 64 + wid * 16;
    const int n0 = blockIdx.x * 32;
    const int To = o0 >> 4;
    const int Tn = n0 >> 4;

    f32x4 acc[2];
    acc[0] = (f32x4){0.f, 0.f, 0.f, 0.f};
    acc[1] = acc[0];
#pragma unroll
    for (int kc = 0; kc < 8; ++kc) {
        const s16x8 ah = load8(Wh + ((To * 8 + kc) * 64 + lane) * 8);
        const s16x8 al = load8(Wl + ((To * 8 + kc) * 64 + lane) * 8);
#pragma unroll
        for (int nt = 0; nt < 2; ++nt) {
            const s16x8 bh = load8(Bh + (((Tn + nt) * 8 + kc) * 64 + lane) * 8);
            const s16x8 bl = load8(Bl + (((Tn + nt) * 8 + kc) * 64 + lane) * 8);
            acc[nt] = __builtin_amdgcn_mfma_f32_16x16x32_bf16(ah, bh, acc[nt], 0, 0, 0);
            acc[nt] = __builtin_amdgcn_mfma_f32_16x16x32_bf16(ah, bl, acc[nt], 0, 0, 0);
            acc[nt] = __builtin_amdgcn_mfma_f32_16x16x32_bf16(al, bh, acc[nt], 0, 0, 0);
        }
    }
    const f32x4 b4 = *(const f32x4*)(bias + o0 + grp * 4);
#pragma unroll
    for (int nt = 0; nt < 2; ++nt) {
        const int n = n0 + nt * 16 + lq;
#pragma unroll
        for (int r = 0; r < 4; ++r)
            Y[(o0 + grp * 4 + r) * NPOS + n] = acc[nt][r] + b4[r];
    }
}

extern "C" void kernel_launch(void* const* d_in, const int* in_sizes, int n_in,
                              void* d_out, int out_size, void* d_ws, size_t ws_size,
                              hipStream_t stream) {
    const float* x1 = (const float*)d_in[0];
    const float* x2 = (const float*)d_in[1];
    const float* Wq = (const float*)d_in[2];
    const float* Wk = (const float*)d_in[3];
    const float* Wv = (const float*)d_in[4];
    const float* Wp = (const float*)d_in[5];
    const float* bp = (const float*)d_in[6];
    float* out = (float*)d_out;

    const size_t MB = 1u << 20;
    char* wsc = (char*)d_ws;
    ushort* xt1h = (ushort*)(wsc + 0 * MB);
    ushort* xt1l = (ushort*)(wsc + 2 * MB);
    ushort* xt2h = (ushort*)(wsc + 4 * MB);
    ushort* xt2l = (ushort*)(wsc + 6 * MB);
    ushort* qt   = (ushort*)(wsc + 8 * MB);
    ushort* kt   = (ushort*)(wsc + 10 * MB);
    ushort* vt   = (ushort*)(wsc + 12 * MB);
    ushort* wsp  = (ushort*)(wsc + 14 * MB);   // [4][2][65536] bf16 tiled
    float*  Ml   = (float*)(wsc + 15 * MB);    // [4][8][4096] f32 (l)
    ushort* Opb  = (ushort*)(wsc + 0 * MB);    // [4][4096][256] bf16 (over xt*)
    ushort* fth  = (ushort*)(wsc + 8 * MB);    // over qt (tiled)
    ushort* ftl  = (ushort*)(wsc + 10 * MB);   // over kt (tiled)

    const float qscale = (float)(0.17677669529663687 * 1.4426950408889634);

    convert_kernel<<<dim3(64, 4, 3), 256, 0, stream>>>(
        x1, x2, Wq, Wk, Wv, Wp, xt1h, xt1l, xt2h, xt2l, wsp, qscale);

    gemm_qkv_kernel<<<dim3(128, 12), 256, 0, stream>>>(
        wsp, xt1h, xt1l, xt2h, xt2l, qt, kt, vt);

    attn_mfma_kernel<<<1024, 256, 0, stream>>>(qt, kt, vt, Opb, Ml);

    combine_kernel<<<1024, 256, 0, stream>>>(Opb, Ml, fth, ftl);

    ushort* wph = wsp + 393216;
    ushort* wpl = wsp + 458752;
    gemm_out_kernel<<<dim3(128, 4), 256, 0, stream>>>(
        wph, wpl, fth, ftl, bp, out);
}